// Round 1
// baseline (493.526 us; speedup 1.0000x reference)
//
#include <hip/hip_runtime.h>
#include <hip/hip_bf16.h>

#define B_DIM 32
#define C_DIM 256
#define H_DIM 128
#define W_DIM 256
#define ATT_DIM 256

// ---------------------------------------------------------------------------
// K1: fused AdaptiveMaxPool2d((None,32)) + dense_width  -> hfT (B,H,C)
// One wave (64 lanes) per (b,c,h) row of 256 floats. Window = 8 along W.
// Lane l holds w in [4l,4l+4); window m = lane>>1 covers [8m,8m+8).
__global__ __launch_bounds__(256) void k1_pool_width(
    const float* __restrict__ feat, const float* __restrict__ w_width,
    const float* __restrict__ b_width, float* __restrict__ hfT)
{
  const int lane = threadIdx.x & 63;
  const long r = (long)blockIdx.x * 4 + (threadIdx.x >> 6);   // row = b*C*H + c*H + h
  const float* p = feat + (size_t)r * W_DIM + lane * 4;
  float4 v4 = *reinterpret_cast<const float4*>(p);
  float v = fmaxf(fmaxf(v4.x, v4.y), fmaxf(v4.z, v4.w));
  v = fmaxf(v, __shfl_xor(v, 1));                              // window max (pairs)
  float contrib = (lane & 1) ? 0.0f : v * w_width[lane >> 1];
#pragma unroll
  for (int off = 32; off >= 1; off >>= 1) contrib += __shfl_xor(contrib, off);
  if (lane == 0) {
    int b = (int)(r >> 15);        // / (C*H)
    int c = ((int)r >> 7) & 255;   // (r / H) % C
    int h = (int)r & 127;          // r % H
    hfT[((size_t)(b * H_DIM + h)) * C_DIM + c] = contrib + b_width[0];
  }
}

// ---------------------------------------------------------------------------
// K2: InstanceNorm1d(2ch over H) + Conv1d(2->16, k=15, pad=7) -> convT (B,H,16)
__global__ __launch_bounds__(128) void k2_norm_conv(
    const float* __restrict__ prev, const float* __restrict__ cov,
    const float* __restrict__ conv_w, const float* __restrict__ conv_b,
    float* __restrict__ convT)
{
  const int b = blockIdx.x, h = threadIdx.x;
  const int lane = h & 63, wid = h >> 6;
  __shared__ float n0[H_DIM], n1[H_DIM];
  __shared__ float ws4[2][4];
  __shared__ float cw[16 * 2 * 15];
  for (int i = h; i < 480; i += 128) cw[i] = conv_w[i];
  float x0 = prev[b * H_DIM + h];
  float x1 = cov[b * H_DIM + h];
  x1 = fminf(fmaxf(x1, 0.0f), 1.0f);
  float s0 = x0, q0 = x0 * x0, s1 = x1, q1 = x1 * x1;
#pragma unroll
  for (int off = 32; off >= 1; off >>= 1) {
    s0 += __shfl_xor(s0, off); q0 += __shfl_xor(q0, off);
    s1 += __shfl_xor(s1, off); q1 += __shfl_xor(q1, off);
  }
  if (lane == 0) { ws4[wid][0] = s0; ws4[wid][1] = q0; ws4[wid][2] = s1; ws4[wid][3] = q1; }
  __syncthreads();
  float S0 = ws4[0][0] + ws4[1][0], Q0 = ws4[0][1] + ws4[1][1];
  float S1 = ws4[0][2] + ws4[1][2], Q1 = ws4[0][3] + ws4[1][3];
  const float rH = 1.0f / H_DIM;
  float mu0 = S0 * rH, mu1 = S1 * rH;
  float var0 = Q0 * rH - mu0 * mu0;
  float var1 = Q1 * rH - mu1 * mu1;
  float inv0 = 1.0f / sqrtf(var0 + 1e-5f);
  float inv1 = 1.0f / sqrtf(var1 + 1e-5f);
  n0[h] = (x0 - mu0) * inv0;
  n1[h] = (x1 - mu1) * inv1;
  __syncthreads();
  float o[16];
#pragma unroll
  for (int k = 0; k < 16; k++) o[k] = conv_b[k];
#pragma unroll
  for (int j = 0; j < 15; j++) {
    int hh = h - 7 + j;
    if (hh >= 0 && hh < H_DIM) {
      float f0 = n0[hh], f1 = n1[hh];
#pragma unroll
      for (int k = 0; k < 16; k++)
        o[k] += f0 * cw[k * 30 + j] + f1 * cw[k * 30 + 15 + j];
    }
  }
  float* outp = convT + ((size_t)(b * H_DIM + h)) * 16;
#pragma unroll
  for (int k = 0; k < 16; k++) outp[k] = o[k];
}

// ---------------------------------------------------------------------------
// K2b: hsum[b,a] = hidden_h[0,b,:] @ w_hid[:,a] + b_hid[a] + b_enc[a] + b_cb[a]
__global__ __launch_bounds__(256) void k2b_hsum(
    const float* __restrict__ hidden, const float* __restrict__ w_hid,
    const float* __restrict__ b_hid, const float* __restrict__ b_enc,
    const float* __restrict__ b_cb, float* __restrict__ hsum)
{
  const int b = blockIdx.x, a = threadIdx.x;
  float acc = b_hid[a] + b_enc[a] + b_cb[a];
  const float* hb = hidden + b * 256;
#pragma unroll 4
  for (int d = 0; d < 256; d++) acc += hb[d] * w_hid[d * ATT_DIM + a];
  hsum[b * ATT_DIM + a] = acc;
}

// ---------------------------------------------------------------------------
// K3: s = hfT @ w_enc + convT @ w_cb + hsum; align = tanh(s) @ w_align + b_align
// 16 rows (m) x 256 cols (a) per block; thread t owns column a=t, acc[16].
__global__ __launch_bounds__(256) void k3_gemm_align(
    const float* __restrict__ hfT, const float* __restrict__ convT,
    const float* __restrict__ hsum, const float* __restrict__ w_enc,
    const float* __restrict__ w_cb, const float* __restrict__ w_align,
    const float* __restrict__ b_align, float* __restrict__ align_out)
{
  __shared__ float At[C_DIM][20];   // transposed A tile [k][m], padded
  __shared__ float Ct[16][17];      // conv tile [k][m]
  __shared__ float red[16][ATT_DIM];
  const int tid = threadIdx.x;
  const int m0 = blockIdx.x * 16;   // global row (b*H + h)
  const int b = m0 >> 7;
#pragma unroll
  for (int i = 0; i < 16; i++)
    At[tid][i] = hfT[(size_t)(m0 + i) * C_DIM + tid];
  {
    int m = tid >> 4, k = tid & 15;
    Ct[k][m] = convT[(size_t)m0 * 16 + tid];
  }
  __syncthreads();
  float acc[16];
#pragma unroll
  for (int m = 0; m < 16; m++) acc[m] = 0.0f;
  const float* wep = w_enc + tid;
#pragma unroll 4
  for (int k = 0; k < C_DIM; k++) {
    float bv = wep[k * ATT_DIM];
    const float4 a0 = *reinterpret_cast<const float4*>(&At[k][0]);
    const float4 a1 = *reinterpret_cast<const float4*>(&At[k][4]);
    const float4 a2 = *reinterpret_cast<const float4*>(&At[k][8]);
    const float4 a3 = *reinterpret_cast<const float4*>(&At[k][12]);
    acc[0] += a0.x * bv; acc[1] += a0.y * bv; acc[2] += a0.z * bv; acc[3] += a0.w * bv;
    acc[4] += a1.x * bv; acc[5] += a1.y * bv; acc[6] += a1.z * bv; acc[7] += a1.w * bv;
    acc[8] += a2.x * bv; acc[9] += a2.y * bv; acc[10] += a2.z * bv; acc[11] += a2.w * bv;
    acc[12] += a3.x * bv; acc[13] += a3.y * bv; acc[14] += a3.z * bv; acc[15] += a3.w * bv;
  }
#pragma unroll
  for (int k = 0; k < 16; k++) {
    float bv = w_cb[k * ATT_DIM + tid];
#pragma unroll
    for (int m = 0; m < 16; m++) acc[m] += Ct[k][m] * bv;
  }
  const float hs = hsum[b * ATT_DIM + tid];
  const float wa = w_align[tid];
#pragma unroll
  for (int m = 0; m < 16; m++)
    red[m][tid] = tanhf(acc[m] + hs) * wa;
  __syncthreads();
  const int lane = tid & 63, wid = tid >> 6;
  const float ba = b_align[0];
  for (int m = wid; m < 16; m += 4) {
    float s = red[m][lane] + red[m][lane + 64] + red[m][lane + 128] + red[m][lane + 192];
#pragma unroll
    for (int off = 32; off >= 1; off >>= 1) s += __shfl_xor(s, off);
    if (lane == 0) align_out[m0 + m] = s + ba;
  }
}

// ---------------------------------------------------------------------------
// K4: softmax over H per batch -> attn (written straight into d_out slot)
__global__ __launch_bounds__(128) void k4_softmax(
    const float* __restrict__ align, float* __restrict__ attn)
{
  const int b = blockIdx.x, h = threadIdx.x;
  const int lane = h & 63, wid = h >> 6;
  __shared__ float sm[2], ss[2];
  float x = align[b * H_DIM + h];
  float m = x;
#pragma unroll
  for (int off = 32; off >= 1; off >>= 1) m = fmaxf(m, __shfl_xor(m, off));
  if (lane == 0) sm[wid] = m;
  __syncthreads();
  m = fmaxf(sm[0], sm[1]);
  float e = expf(x - m);
  float s = e;
#pragma unroll
  for (int off = 32; off >= 1; off >>= 1) s += __shfl_xor(s, off);
  if (lane == 0) ss[wid] = s;
  __syncthreads();
  s = ss[0] + ss[1];
  attn[b * H_DIM + h] = e / s;
}

// ---------------------------------------------------------------------------
// K5: context[b,c,w] = sum_h features[b,c,h,w] * attn[b,h]
// One block per (b,c); 4 wave-groups stride over h; float4 over w.
__global__ __launch_bounds__(256) void k5_context(
    const float* __restrict__ feat, const float* __restrict__ attn,
    float* __restrict__ ctx)
{
  const int bc = blockIdx.x;        // b*C + c
  const int b = bc >> 8;
  const int tid = threadIdx.x;
  __shared__ float at[H_DIM];
  if (tid < H_DIM) at[tid] = attn[(b << 7) + tid];
  __syncthreads();
  const int g = tid >> 6, lane = tid & 63;
  const float* base = feat + (size_t)bc * H_DIM * W_DIM;
  float4 acc = make_float4(0.f, 0.f, 0.f, 0.f);
  for (int h = g; h < H_DIM; h += 4) {
    float4 v = *reinterpret_cast<const float4*>(base + h * W_DIM + lane * 4);
    float a = at[h];
    acc.x += v.x * a; acc.y += v.y * a; acc.z += v.z * a; acc.w += v.w * a;
  }
  __shared__ float4 part[4][64];
  part[g][lane] = acc;
  __syncthreads();
  if (tid < 64) {
    float4 r0 = part[0][tid], r1 = part[1][tid], r2 = part[2][tid], r3 = part[3][tid];
    float4 o;
    o.x = r0.x + r1.x + r2.x + r3.x;
    o.y = r0.y + r1.y + r2.y + r3.y;
    o.z = r0.z + r1.z + r2.z + r3.z;
    o.w = r0.w + r1.w + r2.w + r3.w;
    *reinterpret_cast<float4*>(ctx + (size_t)bc * W_DIM + tid * 4) = o;
  }
}

// ---------------------------------------------------------------------------
extern "C" void kernel_launch(void* const* d_in, const int* in_sizes, int n_in,
                              void* d_out, int out_size, void* d_ws, size_t ws_size,
                              hipStream_t stream)
{
  const float* feat    = (const float*)d_in[0];
  const float* prev    = (const float*)d_in[1];
  const float* cov     = (const float*)d_in[2];
  const float* hidden  = (const float*)d_in[3];
  const float* w_width = (const float*)d_in[4];
  const float* b_width = (const float*)d_in[5];
  const float* w_enc   = (const float*)d_in[6];
  const float* b_enc   = (const float*)d_in[7];
  const float* conv_w  = (const float*)d_in[8];
  const float* conv_b  = (const float*)d_in[9];
  const float* w_cb    = (const float*)d_in[10];
  const float* b_cb    = (const float*)d_in[11];
  const float* w_hid   = (const float*)d_in[12];
  const float* b_hid   = (const float*)d_in[13];
  const float* w_align = (const float*)d_in[14];
  const float* b_align = (const float*)d_in[15];

  float* ctx_out  = (float*)d_out;                                   // (B,C,W)
  float* attn_out = (float*)d_out + (size_t)B_DIM * C_DIM * W_DIM;   // (B,H)

  float* ws    = (float*)d_ws;
  float* hfT   = ws;                 // (B,H,C)  = 1048576 floats
  float* convT = hfT + 1048576;      // (B,H,16) = 65536
  float* hsum  = convT + 65536;      // (B,ATT)  = 8192
  float* align = hsum + 8192;        // (B,H)    = 4096

  k1_pool_width<<<dim3((B_DIM * C_DIM * H_DIM) / 4), dim3(256), 0, stream>>>(
      feat, w_width, b_width, hfT);
  k2_norm_conv<<<dim3(B_DIM), dim3(128), 0, stream>>>(prev, cov, conv_w, conv_b, convT);
  k2b_hsum<<<dim3(B_DIM), dim3(256), 0, stream>>>(hidden, w_hid, b_hid, b_enc, b_cb, hsum);
  k3_gemm_align<<<dim3((B_DIM * H_DIM) / 16), dim3(256), 0, stream>>>(
      hfT, convT, hsum, w_enc, w_cb, w_align, b_align, align);
  k4_softmax<<<dim3(B_DIM), dim3(128), 0, stream>>>(align, attn_out);
  k5_context<<<dim3(B_DIM * C_DIM), dim3(256), 0, stream>>>(feat, attn_out, ctx_out);
}

// Round 2
// 400.650 us; speedup vs baseline: 1.2318x; 1.2318x over previous
//
#include <hip/hip_runtime.h>
#include <hip/hip_bf16.h>

#define B_DIM 32
#define C_DIM 256
#define H_DIM 128
#define W_DIM 256
#define ATT_DIM 256

// ---------------------------------------------------------------------------
// KA: heterogeneous fused kernel.
//   blocks [0, 8192):     K1 pool+width for (b,c)=bid -> hf in (B,C,H) layout
//   blocks [8192, 8224):  K2 InstanceNorm + Conv1d for b=bid-8192 -> convT (B,H,16)
//   blocks [8224, 8256):  K2b hidden GEMV + fused biases for b=bid-8224 -> hsum (B,ATT)
__global__ __launch_bounds__(256) void ka_fused(
    const float* __restrict__ feat, const float* __restrict__ w_width,
    const float* __restrict__ b_width,
    const float* __restrict__ prev, const float* __restrict__ cov,
    const float* __restrict__ conv_w, const float* __restrict__ conv_b,
    const float* __restrict__ hidden, const float* __restrict__ w_hid,
    const float* __restrict__ b_hid, const float* __restrict__ b_enc,
    const float* __restrict__ b_cb,
    float* __restrict__ hf, float* __restrict__ convT, float* __restrict__ hsum)
{
  const int tid = threadIdx.x;
  const int bid = blockIdx.x;

  if (bid < 8192) {
    // ---- K1: one block per (b,c); 4 waves x 32 rows; row = 256 floats ----
    __shared__ float res[H_DIM];
    const int lane = tid & 63, wid = tid >> 6;
    const float wv = w_width[lane >> 1] * 0.5f;   // halved: pair-sum counts twice
    const float bw = b_width[0];
    const float* base = feat + (size_t)bid * H_DIM * W_DIM + lane * 4;
#pragma unroll 4
    for (int i = 0; i < 32; i++) {
      const int h = wid + 4 * i;
      float4 v4 = *reinterpret_cast<const float4*>(base + (size_t)h * W_DIM);
      float v = fmaxf(fmaxf(v4.x, v4.y), fmaxf(v4.z, v4.w));
      v = fmaxf(v, __shfl_xor(v, 1));            // window max (8 wide = 2 lanes)
      float contrib = v * wv;
#pragma unroll
      for (int off = 32; off >= 1; off >>= 1) contrib += __shfl_xor(contrib, off);
      if (lane == 0) res[h] = contrib + bw;
    }
    __syncthreads();
    if (tid < H_DIM)
      hf[(size_t)bid * H_DIM + tid] = res[tid];  // coalesced 512B store
  } else if (bid < 8224) {
    // ---- K2: InstanceNorm1d(2ch over H) + Conv1d(2->16,k15,p7) ----
    const int b = bid - 8192;
    __shared__ float n0[H_DIM], n1[H_DIM];
    __shared__ float ws4[2][4];
    __shared__ float cw[480];
    for (int i = tid; i < 480; i += 256) cw[i] = conv_w[i];
    const int lane = tid & 63, wv2 = tid >> 6;
    float x0 = 0.f, x1 = 0.f;
    if (tid < 128) {
      x0 = prev[b * H_DIM + tid];
      x1 = cov[b * H_DIM + tid];
      x1 = fminf(fmaxf(x1, 0.0f), 1.0f);
      float s0 = x0, q0 = x0 * x0, s1 = x1, q1 = x1 * x1;
#pragma unroll
      for (int off = 32; off >= 1; off >>= 1) {
        s0 += __shfl_xor(s0, off); q0 += __shfl_xor(q0, off);
        s1 += __shfl_xor(s1, off); q1 += __shfl_xor(q1, off);
      }
      if (lane == 0) { ws4[wv2][0] = s0; ws4[wv2][1] = q0; ws4[wv2][2] = s1; ws4[wv2][3] = q1; }
    }
    __syncthreads();
    if (tid < 128) {
      float S0 = ws4[0][0] + ws4[1][0], Q0 = ws4[0][1] + ws4[1][1];
      float S1 = ws4[0][2] + ws4[1][2], Q1 = ws4[0][3] + ws4[1][3];
      const float rH = 1.0f / H_DIM;
      float mu0 = S0 * rH, mu1 = S1 * rH;
      float inv0 = 1.0f / sqrtf(Q0 * rH - mu0 * mu0 + 1e-5f);
      float inv1 = 1.0f / sqrtf(Q1 * rH - mu1 * mu1 + 1e-5f);
      n0[tid] = (x0 - mu0) * inv0;
      n1[tid] = (x1 - mu1) * inv1;
    }
    __syncthreads();
    if (tid < 128) {
      float o[16];
#pragma unroll
      for (int k = 0; k < 16; k++) o[k] = conv_b[k];
#pragma unroll
      for (int j = 0; j < 15; j++) {
        int hh = tid - 7 + j;
        if (hh >= 0 && hh < H_DIM) {
          float f0 = n0[hh], f1 = n1[hh];
#pragma unroll
          for (int k = 0; k < 16; k++)
            o[k] += f0 * cw[k * 30 + j] + f1 * cw[k * 30 + 15 + j];
        }
      }
      float* outp = convT + ((size_t)(b * H_DIM + tid)) * 16;
#pragma unroll
      for (int k = 0; k < 16; k++) outp[k] = o[k];
    }
  } else {
    // ---- K2b: hsum[b,a] = hidden[b,:] @ w_hid[:,a] + b_hid + b_enc + b_cb ----
    const int b = bid - 8224;
    const int a = tid;
    float acc = b_hid[a] + b_enc[a] + b_cb[a];
    const float* hb = hidden + b * 256;
#pragma unroll 4
    for (int d = 0; d < 256; d++) acc += hb[d] * w_hid[d * ATT_DIM + a];
    hsum[b * ATT_DIM + a] = acc;
  }
}

// ---------------------------------------------------------------------------
// KB: s = hf^T @ w_enc + convT @ w_cb + hsum; align = tanh(s) @ w_align + b_align
// 8 rows x 256 cols per block; thread t owns column a=t.  hf is (B,C,H).
__global__ __launch_bounds__(256) void kb_gemm_align(
    const float* __restrict__ hf, const float* __restrict__ convT,
    const float* __restrict__ hsum, const float* __restrict__ w_enc,
    const float* __restrict__ w_cb, const float* __restrict__ w_align,
    const float* __restrict__ b_align, float* __restrict__ align_out)
{
  __shared__ float At[C_DIM][12];   // [k=c][m], pitch 12 keeps float4 alignment
  __shared__ float Ct[16][9];       // [k][m]
  __shared__ float red[8][ATT_DIM];
  const int tid = threadIdx.x;
  const int m0 = blockIdx.x * 8;    // global row (b*H + h)
  const int b = m0 >> 7;
  const int h0 = m0 & 127;
  // A tile: thread t loads hf[b, c=t, h0:h0+8] (64B contiguous per thread)
  const float* hp = hf + ((size_t)(b * C_DIM + tid)) * H_DIM + h0;
  float4 r0 = *reinterpret_cast<const float4*>(hp);
  float4 r1 = *reinterpret_cast<const float4*>(hp + 4);
  *reinterpret_cast<float4*>(&At[tid][0]) = r0;
  *reinterpret_cast<float4*>(&At[tid][4]) = r1;
  if (tid < 128) {
    int m = tid >> 4, k = tid & 15;
    Ct[k][m] = convT[(size_t)(b * H_DIM + h0) * 16 + tid];
  }
  __syncthreads();
  float acc[8];
#pragma unroll
  for (int m = 0; m < 8; m++) acc[m] = 0.0f;
  const float* wep = w_enc + tid;
#pragma unroll 4
  for (int k = 0; k < C_DIM; k++) {
    float bv = wep[k * ATT_DIM];
    const float4 a0 = *reinterpret_cast<const float4*>(&At[k][0]);
    const float4 a1 = *reinterpret_cast<const float4*>(&At[k][4]);
    acc[0] += a0.x * bv; acc[1] += a0.y * bv; acc[2] += a0.z * bv; acc[3] += a0.w * bv;
    acc[4] += a1.x * bv; acc[5] += a1.y * bv; acc[6] += a1.z * bv; acc[7] += a1.w * bv;
  }
#pragma unroll
  for (int k = 0; k < 16; k++) {
    float bv = w_cb[k * ATT_DIM + tid];
#pragma unroll
    for (int m = 0; m < 8; m++) acc[m] += Ct[k][m] * bv;
  }
  const float hs = hsum[b * ATT_DIM + tid];
  const float wa = w_align[tid];
#pragma unroll
  for (int m = 0; m < 8; m++)
    red[m][tid] = tanhf(acc[m] + hs) * wa;
  __syncthreads();
  const int lane = tid & 63, wid = tid >> 6;
  const float ba = b_align[0];
  for (int m = wid; m < 8; m += 4) {
    float s = red[m][lane] + red[m][lane + 64] + red[m][lane + 128] + red[m][lane + 192];
#pragma unroll
    for (int off = 32; off >= 1; off >>= 1) s += __shfl_xor(s, off);
    if (lane == 0) align_out[m0 + m] = s + ba;
  }
}

// ---------------------------------------------------------------------------
// KC: in-block softmax over H (from align, 4KB L2-resident) + context reduce.
// Reverse block order: starts on the features data KA touched last (L3 reuse).
// Blocks with c==0 also write attn to its d_out slot.
__global__ __launch_bounds__(256) void kc_context(
    const float* __restrict__ feat, const float* __restrict__ align,
    float* __restrict__ attn_out, float* __restrict__ ctx)
{
  const int bc = 8191 - blockIdx.x;   // b*C + c, reversed
  const int b = bc >> 8, c = bc & 255;
  const int tid = threadIdx.x;
  __shared__ float al[H_DIM], at[H_DIM];
  if (tid < H_DIM) al[tid] = align[(b << 7) + tid];
  __syncthreads();
  if (tid < 64) {
    float a0 = al[tid], a1 = al[tid + 64];
    float mx = fmaxf(a0, a1);
#pragma unroll
    for (int off = 32; off >= 1; off >>= 1) mx = fmaxf(mx, __shfl_xor(mx, off));
    float e0 = expf(a0 - mx), e1 = expf(a1 - mx);
    float s = e0 + e1;
#pragma unroll
    for (int off = 32; off >= 1; off >>= 1) s += __shfl_xor(s, off);
    float inv = 1.0f / s;
    at[tid] = e0 * inv;
    at[tid + 64] = e1 * inv;
  }
  __syncthreads();
  if (c == 0 && tid < H_DIM) attn_out[(b << 7) + tid] = at[tid];
  const int g = tid >> 6, lane = tid & 63;
  const float* base = feat + (size_t)bc * H_DIM * W_DIM + lane * 4;
  float4 acc = make_float4(0.f, 0.f, 0.f, 0.f);
#pragma unroll 4
  for (int h = g; h < H_DIM; h += 4) {
    float4 v = *reinterpret_cast<const float4*>(base + (size_t)h * W_DIM);
    float a = at[h];
    acc.x += v.x * a; acc.y += v.y * a; acc.z += v.z * a; acc.w += v.w * a;
  }
  __shared__ float4 part[4][64];
  part[g][lane] = acc;
  __syncthreads();
  if (tid < 64) {
    float4 r0 = part[0][tid], r1 = part[1][tid], r2 = part[2][tid], r3 = part[3][tid];
    float4 o;
    o.x = r0.x + r1.x + r2.x + r3.x;
    o.y = r0.y + r1.y + r2.y + r3.y;
    o.z = r0.z + r1.z + r2.z + r3.z;
    o.w = r0.w + r1.w + r2.w + r3.w;
    *reinterpret_cast<float4*>(ctx + (size_t)bc * W_DIM + tid * 4) = o;
  }
}

// ---------------------------------------------------------------------------
extern "C" void kernel_launch(void* const* d_in, const int* in_sizes, int n_in,
                              void* d_out, int out_size, void* d_ws, size_t ws_size,
                              hipStream_t stream)
{
  const float* feat    = (const float*)d_in[0];
  const float* prev    = (const float*)d_in[1];
  const float* cov     = (const float*)d_in[2];
  const float* hidden  = (const float*)d_in[3];
  const float* w_width = (const float*)d_in[4];
  const float* b_width = (const float*)d_in[5];
  const float* w_enc   = (const float*)d_in[6];
  const float* b_enc   = (const float*)d_in[7];
  const float* conv_w  = (const float*)d_in[8];
  const float* conv_b  = (const float*)d_in[9];
  const float* w_cb    = (const float*)d_in[10];
  const float* b_cb    = (const float*)d_in[11];
  const float* w_hid   = (const float*)d_in[12];
  const float* b_hid   = (const float*)d_in[13];
  const float* w_align = (const float*)d_in[14];
  const float* b_align = (const float*)d_in[15];

  float* ctx_out  = (float*)d_out;                                   // (B,C,W)
  float* attn_out = (float*)d_out + (size_t)B_DIM * C_DIM * W_DIM;   // (B,H)

  float* ws    = (float*)d_ws;
  float* hf    = ws;                 // (B,C,H)  = 1048576 floats
  float* convT = hf + 1048576;       // (B,H,16) = 65536
  float* hsum  = convT + 65536;      // (B,ATT)  = 8192
  float* align = hsum + 8192;        // (B,H)    = 4096

  ka_fused<<<dim3(8192 + 32 + 32), dim3(256), 0, stream>>>(
      feat, w_width, b_width, prev, cov, conv_w, conv_b,
      hidden, w_hid, b_hid, b_enc, b_cb, hf, convT, hsum);
  kb_gemm_align<<<dim3((B_DIM * H_DIM) / 8), dim3(256), 0, stream>>>(
      hf, convT, hsum, w_enc, w_cb, w_align, b_align, align);
  kc_context<<<dim3(B_DIM * C_DIM), dim3(256), 0, stream>>>(
      feat, align, attn_out, ctx_out);
}